// Round 2
// 318.000 us; speedup vs baseline: 1.0502x; 1.0502x over previous
//
#include <hip/hip_runtime.h>

// Triline interpolation, B=1M points, N=512 rows, C=64 channels, fp32.
//
// v2 (resubmit after infra failure): serve the random row gathers from LDS.
// Previous kernel was L2-read-bound: 1.6 GB of random 256 B row reads
// contending with the 268 MB write stream in L2 (~167 us). LDS (CU-private,
// 69 TB/s aggregate) removes that entirely; kernel becomes a pure HBM
// write stream (~45-60 us floor).
//
// Decomposition: 64 channels split into 4 groups x 16 ch. Per-block LDS
// slice = 3 lines x 512 rows x 16 ch x 4 B = 96 KB payload (120 KB with
// bank-spread stride). Grid = 4 groups x 128 point-ranges; bid = g*128+pr
// with 128 % 8 == 0 so all 4 channel-group blocks of a point range land on
// the same XCD (round-robin dispatch): their 64 B output quarters merge to
// full 128 B lines in that XCD's L2, and coords reads are shared via L2.

typedef float f4 __attribute__((ext_vector_type(4)));

constexpr int kN       = 512;
constexpr int kC4      = 16;   // float4 chunks per 64-channel row
constexpr int kGroups  = 4;    // channel groups (16 ch = 4 f4 chunks each)
constexpr int kPr      = 128;  // point ranges; multiple of 8 (XCD grouping)
constexpr int kRowF    = 20;   // LDS row stride in floats (80 B): (20*r) mod 32
                               // cycles all 8 bank-quads with period 8 ->
                               // random-row ds_read_b128 ~2-way aliasing (free)
constexpr int kThreads = 1024; // 120 KB LDS -> 1 block/CU, 16 waves/CU

__global__ __launch_bounds__(kThreads) void triline_lds_kernel(
    const float* __restrict__ coords,
    const f4* __restrict__ xl,
    const f4* __restrict__ yl,
    const f4* __restrict__ zl,
    const float* __restrict__ grid,
    f4* __restrict__ out,
    int B)
{
    __shared__ float sm[3 * kN * kRowF];   // 122,880 B = 120 KB

    const int bid = blockIdx.x;
    const int g   = bid / kPr;   // channel group 0..3
    const int pr  = bid % kPr;   // point range  0..127

    // ---- Stage this group's 16-channel slice of all 3 line tables ----
    // 512 rows x 4 chunks per line; 1024 threads -> 2 iterations.
    for (int i = threadIdx.x; i < kN * 4; i += kThreads) {
        const int r   = i >> 2;
        const int k   = i & 3;
        const int dst = r * kRowF + k * 4;
        const int src = r * kC4 + g * 4 + k;
        *(f4*)&sm[dst]                  = xl[src];
        *(f4*)&sm[kN * kRowF + dst]     = yl[src];
        *(f4*)&sm[2 * kN * kRowF + dst] = zl[src];
    }
    __syncthreads();
    // LDS is read-only from here on: no barriers in the main loop.

    const float g0     = grid[0];
    const float inv_dg = 1.0f / (grid[1] - g0);

    const int p = threadIdx.x >> 2;  // point slot 0..255 within an iteration
    const int k = threadIdx.x & 3;   // f4 chunk within the 16-ch group

    const int per  = (B + kPr - 1) / kPr;   // points per range (8192 at B=1M)
    const int b0   = pr * per;
    const int bend = min(b0 + per, B);

    const float* sx = sm;
    const float* sy = sm + kN * kRowF;
    const float* sz = sm + 2 * kN * kRowF;

    int   b  = b0 + p;
    float cx = 0.0f, cy = 0.0f, cz = 0.0f;
    if (b < bend) {
        cx = coords[3 * b + 0];
        cy = coords[3 * b + 1];
        cz = coords[3 * b + 2];
    }

    while (b < bend) {
        // Software-prefetch next iteration's coords (hides HBM/L2 latency;
        // only serial dependence in the loop).
        const int bn = b + 256;
        float nx = 0.0f, ny = 0.0f, nz = 0.0f;
        if (bn < bend) {
            nx = coords[3 * bn + 0];
            ny = coords[3 * bn + 1];
            nz = coords[3 * bn + 2];
        }

        const float px = (cx - g0) * inv_dg;
        const float py = (cy - g0) * inv_dg;
        const float pz = (cz - g0) * inv_dg;

        const int ix = min(max((int)floorf(px), 0), kN - 2);
        const int iy = min(max((int)floorf(py), 0), kN - 2);
        const int iz = min(max((int)floorf(pz), 0), kN - 2);

        const float wx = px - (float)ix;
        const float wy = py - (float)iy;
        const float wz = pz - (float)iz;

        // 6 ds_read_b128, ~conflict-free via the 80 B row stride.
        const f4 x0 = *(const f4*)&sx[ix * kRowF + k * 4];
        const f4 x1 = *(const f4*)&sx[ix * kRowF + kRowF + k * 4];
        const f4 y0 = *(const f4*)&sy[iy * kRowF + k * 4];
        const f4 y1 = *(const f4*)&sy[iy * kRowF + kRowF + k * 4];
        const f4 z0 = *(const f4*)&sz[iz * kRowF + k * 4];
        const f4 z1 = *(const f4*)&sz[iz * kRowF + kRowF + k * 4];

        f4 r = x0 + (x1 - x0) * wx;
        r    = r + y0 + (y1 - y0) * wy;
        r    = r + z0 + (z1 - z0) * wz;

        // 64 B per point-group, contiguous; g0/g1 (and g2/g3) blocks on the
        // same XCD merge halves into full 128 B lines in L2 before writeback.
        __builtin_nontemporal_store(r, &out[b * kC4 + g * 4 + k]);

        b  = bn;
        cx = nx; cy = ny; cz = nz;
    }
}

extern "C" void kernel_launch(void* const* d_in, const int* in_sizes, int n_in,
                              void* d_out, int out_size, void* d_ws, size_t ws_size,
                              hipStream_t stream) {
    const float* coords = (const float*)d_in[0];
    const f4*    xl     = (const f4*)d_in[1];
    const f4*    yl     = (const f4*)d_in[2];
    const f4*    zl     = (const f4*)d_in[3];
    const float* grid   = (const float*)d_in[4];
    f4*          out    = (f4*)d_out;

    int B = in_sizes[0] / 3;   // 1048576

    triline_lds_kernel<<<kGroups * kPr, kThreads, 0, stream>>>(
        coords, xl, yl, zl, grid, out, B);
}